// Round 8
// baseline (164.835 us; speedup 1.0000x reference)
//
#include <hip/hip_runtime.h>

typedef unsigned short u16;
typedef unsigned int u32;
typedef _Float16 half8 __attribute__((ext_vector_type(8)));   // MFMA A/B frag
typedef __attribute__((ext_vector_type(4))) float floatx4;    // MFMA acc

#define LSTRIDE 72            // u16 per LDS row (64 data + 8 pad); bank-clean
#define TILE (128 * LSTRIDE)  // u16 per tile (18432 B)

// ---------------------------------------------------------------------------
// Single dispatch. 4 blocks/CU pinned by LDS (4 x 38.4KB = 153.6 <= 160KB).
// launch_bounds(256,3): releases the (256,4) archVGPR=64 cap that caused
// scratch spills in R4-R6 (R7 evidence: (256,2) -> VGPR 120, FETCH ideal).
//   out[sub][p*8+q][o] = S*acc - K1*csum[o],  S = 2/255, K1 = 1024*S+1
//   acc = sum_m fp16(1024 + w[q][m]) * fp16(Wpad[m - p][o])
// BM=128 (16 subs x 8 q), BN=128 (2 p x 64 o), BK=64. 4 waves 2x2, 64x64.
// Per iter: ks0 -> wload(kc+1, wave-uniform-branch fast path) -> ks1 ->
//   xload(kc+1) + wfinish (csum+cvt+pack, MFMA shadow; only hp[9]+x[9]
//   cross the barrier) -> barrier -> astage + bwrite -> barrier.
// Epilogue: LDS-staged two halves -> fully-coalesced 1KB/wave-instr stores.
// ---------------------------------------------------------------------------
__global__ __launch_bounds__(256, 3) void byteformer_fused(
    const int* __restrict__ x, const float* __restrict__ Wm,
    float* __restrict__ out) {
  __shared__ __align__(16) u16 arena[2 * TILE];   // As | Bs = 36864 B
  __shared__ float part[256];
  __shared__ float csumsh[64];
  u16* As = arena;
  u16* Bs = arena + TILE;

  const int t = threadIdx.x;
  const int mtile = blockIdx.x;        // 0..127 (16 sub-blocks each)
  const int y = blockIdx.y;            // 0..7: p in {2y, 2y+1}

  const int wave = t >> 6, lane = t & 63;
  const int wm = wave >> 1, wn = wave & 1;
  const int quad = lane >> 4, l16 = lane & 15;

  // A staging: thread -> (sub, k-group, q-half)
  const int sA_sub = t >> 4;           // 0..15
  const int sA_kg  = (t >> 1) & 7;     // 0..7
  const int sA_qh  = t & 1;            // 0..1
  const long xrow = ((long)mtile * 16 + sA_sub) * 512;

  floatx4 acc[4][4];
  #pragma unroll
  for (int mt = 0; mt < 4; ++mt)
    #pragma unroll
    for (int nt = 0; nt < 4; ++nt)
      acc[mt][nt] = floatx4{0.f, 0.f, 0.f, 0.f};

  float csum_local = 0.0f;

  // ---- register prefetch state
  int4 ca, cb; int cc;                 // x bytes (9 ints)
  float fv[17];                        // W rows (f32, cvt'd in wfinish)
  u32 hp[9];                           // packed fp16 pairs (cross-barrier)

  auto xload = [&](int kc) {
    const int base = kc * 64 + sA_kg * 8;
    ca = *(const int4*)&x[xrow + base];
    cb = *(const int4*)&x[xrow + base + 4];
    cc = (base + 8 < 512) ? x[xrow + base + 8] : 0;
  };

  // wave-uniform branch: interior waves (30/32 wave-iters) take the
  // no-predication path: one base addr + 17 offset loads, zero per-elem VALU.
  auto wload = [&](int kc) {
    const int cbase = kc * 64 + 16 * wave - 2 * y - 1;
    if (cbase >= 0 && cbase + 16 < 496) {
      const float* wp = &Wm[cbase * 64 + lane];
      #pragma unroll
      for (int j = 0; j < 17; ++j) fv[j] = wp[j * 64];
    } else {
      #pragma unroll
      for (int j = 0; j < 17; ++j) {
        const int c = cbase + j;
        fv[j] = (c >= 0 && c < 496) ? Wm[c * 64 + lane] : 0.0f;
      }
    }
  };

  auto wfinish = [&]() {               // csum + cvt + pack (MFMA shadow)
    #pragma unroll
    for (int j = 1; j <= 16; ++j) csum_local += fv[j];  // pp=0: full W
    #pragma unroll
    for (int i = 0; i < 8; ++i) {
      u32 h0 = __builtin_bit_cast(unsigned short, (_Float16)fv[2 * i]);
      u32 h1 = __builtin_bit_cast(unsigned short, (_Float16)fv[2 * i + 1]);
      hp[i] = h0 | (h1 << 16);
    }
    hp[8] = (u32)__builtin_bit_cast(unsigned short, (_Float16)fv[16]);
  };

  // bytes -> windows -> fp16(1024+v) via 0x6400|v; P-trick; b128 writes
  auto astage = [&]() {
    const u32 c0 = (u32)ca.x, c1 = (u32)ca.y, c2 = (u32)ca.z, c3 = (u32)ca.w;
    const u32 c4 = (u32)cb.x, c5 = (u32)cb.y, c6 = (u32)cb.z, c7 = (u32)cb.w;
    const u32 c8 = (u32)cc;
    const u32 P0 = ((c0 << 8) | c1) | (((c1 << 8) | c2) << 16);
    const u32 P1 = ((c2 << 8) | c3) | (((c3 << 8) | c4) << 16);
    const u32 P2 = ((c4 << 8) | c5) | (((c5 << 8) | c6) << 16);
    const u32 P3 = ((c6 << 8) | c7) | (((c7 << 8) | c8) << 16);
    u16* arow = &As[(sA_sub * 8 + sA_qh * 4) * LSTRIDE + sA_kg * 8];
    #pragma unroll
    for (int qi = 0; qi < 4; ++qi) {
      const int sh = 8 - (sA_qh * 4 + qi);
      int4 d;
      d.x = (int)(((P0 >> sh) & 0x00FF00FFu) | 0x64006400u);
      d.y = (int)(((P1 >> sh) & 0x00FF00FFu) | 0x64006400u);
      d.z = (int)(((P2 >> sh) & 0x00FF00FFu) | 0x64006400u);
      d.w = (int)(((P3 >> sh) & 0x00FF00FFu) | 0x64006400u);
      *(int4*)(arow + qi * LSTRIDE) = d;   // rows 16B-aligned (144B pitch)
    }
  };

  // hp -> two m-groups x two p-shifts, one b128 write each
  auto bwrite = [&]() {
    #pragma unroll
    for (int g = 0; g < 2; ++g) {
      const int mgrp = 2 * wave + g;
      int4 d1;                          // pp=1: even pairs, direct
      d1.x = (int)hp[4 * g + 0];
      d1.y = (int)hp[4 * g + 1];
      d1.z = (int)hp[4 * g + 2];
      d1.w = (int)hp[4 * g + 3];
      *(int4*)&Bs[(64 + lane) * LSTRIDE + mgrp * 8] = d1;
      int4 d0;                          // pp=0: odd pairs, alignbit extract
      d0.x = (int)((hp[4 * g + 0] >> 16) | (hp[4 * g + 1] << 16));
      d0.y = (int)((hp[4 * g + 1] >> 16) | (hp[4 * g + 2] << 16));
      d0.z = (int)((hp[4 * g + 2] >> 16) | (hp[4 * g + 3] << 16));
      d0.w = (int)((hp[4 * g + 3] >> 16) | (hp[4 * g + 4] << 16));
      *(int4*)&Bs[lane * LSTRIDE + mgrp * 8] = d0;
    }
  };

  auto compute_ks = [&](int ks) {
    const int koff = ks * 32 + quad * 8;
    half8 bf[4];
    #pragma unroll
    for (int nt = 0; nt < 4; ++nt)
      bf[nt] = *(const half8*)&Bs[(wn * 64 + nt * 16 + l16) * LSTRIDE + koff];
    #pragma unroll
    for (int mt = 0; mt < 4; ++mt) {
      half8 af = *(const half8*)&As[(wm * 64 + mt * 16 + l16) * LSTRIDE + koff];
      #pragma unroll
      for (int nt = 0; nt < 4; ++nt)
        acc[mt][nt] = __builtin_amdgcn_mfma_f32_16x16x32_f16(
            af, bf[nt], acc[mt][nt], 0, 0, 0);
    }
  };

  // ---- prologue: stage kc=0 (one-time exposed latency)
  xload(0); wload(0);
  wfinish();
  astage(); bwrite();
  __syncthreads();

  // ---- main loop: single-buffered, 2 barriers/iter; loads in MFMA shadow
  for (int kc = 0; kc < 8; ++kc) {
    compute_ks(0);
    if (kc < 7) wload(kc + 1);         // ~17 loads, latency under ks1
    compute_ks(1);
    if (kc < 7) { xload(kc + 1); wfinish(); }  // cvt in MFMA/drain shadow
    __syncthreads();                   // all reads of tile kc done
    if (kc < 7) {
      astage();                        // consume arrived x (pure VALU)
      bwrite();                        // hp -> LDS
      __syncthreads();                 // tile kc+1 published
    }
  }

  // ---- csum reduction -> K1 * colsum(W)
  const float S = 2.0f / 255.0f;
  const float K1 = 1024.0f * S + 1.0f;
  part[t] = csum_local;
  __syncthreads();                     // also: all tile reads done, arena free
  if (t < 64)
    csumsh[t] = K1 * (part[t] + part[t + 64] + part[t + 128] + part[t + 192]);
  __syncthreads();

  float cs[4];
  #pragma unroll
  for (int nt = 0; nt < 4; ++nt) cs[nt] = csumsh[nt * 16 + l16];

  // ---- epilogue: two halves (8 subs each) staged in LDS (pitch 1040 f32),
  // then fully-coalesced stores: 64 lanes x 16B = 1KB contiguous per instr.
  float* ep = (float*)arena;           // 33280 B per half <= 36864
  #pragma unroll
  for (int h = 0; h < 2; ++h) {
    if (wm == h) {                     // waves wm==h own subs h*8..h*8+7
      #pragma unroll
      for (int mt = 0; mt < 4; ++mt)
        #pragma unroll
        for (int i = 0; i < 4; ++i) {
          const int mr = mt * 16 + quad * 4 + i;   // 0..63 local
          const int rowbase = (mr >> 3) * 1040 + wn * 512 + (mr & 7) * 64 + l16;
          #pragma unroll
          for (int nt = 0; nt < 4; ++nt)
            ep[rowbase + nt * 16] = __builtin_fmaf(S, acc[mt][nt][i], -cs[nt]);
        }
    }
    __syncthreads();
    const long outb =
        ((long)mtile * 16 + (long)h * 8) * 8192 + (long)y * 1024;
    #pragma unroll
    for (int k2 = 0; k2 < 8; ++k2) {
      const float4 v =
          *(const float4*)((const char*)ep + k2 * 4160 + wave * 1024 + lane * 16);
      *(float4*)&out[outb + (long)k2 * 8192 + wave * 256 + lane * 4] = v;
    }
    if (h == 0) __syncthreads();       // half-0 LDS reads done before re-stage
  }
}

extern "C" void kernel_launch(void* const* d_in, const int* in_sizes, int n_in,
                              void* d_out, int out_size, void* d_ws, size_t ws_size,
                              hipStream_t stream) {
  const int* x = (const int*)d_in[0];        // (256, 4096) byte values as int32
  const float* Wm = (const float*)d_in[1];   // (496, 64) fp32
  float* out = (float*)d_out;                // (256, 8, 128, 64) fp32
  byteformer_fused<<<dim3(128, 8), dim3(256), 0, stream>>>(x, Wm, out);
}

// Round 9
// 96.136 us; speedup vs baseline: 1.7146x; 1.7146x over previous
//
#include <hip/hip_runtime.h>

typedef unsigned short u16;
typedef unsigned int u32;
typedef _Float16 half8 __attribute__((ext_vector_type(8)));   // MFMA A/B frag
typedef __attribute__((ext_vector_type(4))) float floatx4;    // MFMA acc

#define LSTRIDE 72            // u16 per LDS row (64 data + 8 pad); bank-clean
#define TILE (128 * LSTRIDE)  // u16 per tile (18432 B)

// ---------------------------------------------------------------------------
// R0 structure (best measured: 44.6us): exposed stage-phase loads, zero
// cross-phase register liveness, 2 barriers/iter, 4 blocks/CU TLP hides
// latency. launch_bounds(256,4): VGPR 64, no scratch (R0-verified).
//   out[sub][p*8+q][o] = S*acc - K1*csum[o],  S = 2/255, K1 = 1024*S+1
//   acc = sum_m fp16(1024 + w[q][m]) * fp16(Wpad[m - p][o])
// BM=128 (16 subs x 8 q), BN=128 (2 p x 64 o), BK=64. 4 waves 2x2, 64x64.
// Grafts (verified-correct, pressure-neutral):
//  - coalesced LDS-staged epilogue (R3/R6/R7: WRITE 90.6 -> 68.6MB)
//  - wave-uniform fast-path wload (bounds predicate only needed at
//    (kc=0,wave0) and (kc=7,wave3))
//  - P-trick A-stage (R1+)
// ---------------------------------------------------------------------------
__global__ __launch_bounds__(256, 4) void byteformer_fused(
    const int* __restrict__ x, const float* __restrict__ Wm,
    float* __restrict__ out) {
  __shared__ __align__(16) u16 arena[2 * TILE];   // As | Bs = 36864 B
  __shared__ float part[256];
  __shared__ float csumsh[64];
  u16* As = arena;
  u16* Bs = arena + TILE;

  const int t = threadIdx.x;
  const int mtile = blockIdx.x;        // 0..127 (16 sub-blocks each)
  const int y = blockIdx.y;            // 0..7: p in {2y, 2y+1}

  const int wave = t >> 6, lane = t & 63;
  const int wm = wave >> 1, wn = wave & 1;
  const int quad = lane >> 4, l16 = lane & 15;

  // A staging: thread -> (sub, k-group, q-half)
  const int sA_sub = t >> 4;           // 0..15
  const int sA_kg  = (t >> 1) & 7;     // 0..7
  const int sA_qh  = t & 1;            // 0..1
  const long xrow = ((long)mtile * 16 + sA_sub) * 512;

  floatx4 acc[4][4];
  #pragma unroll
  for (int mt = 0; mt < 4; ++mt)
    #pragma unroll
    for (int nt = 0; nt < 4; ++nt)
      acc[mt][nt] = floatx4{0.f, 0.f, 0.f, 0.f};

  float csum_local = 0.0f;

  for (int kc = 0; kc < 8; ++kc) {
    __syncthreads();                   // previous chunk's LDS reads done

    // ---- stage A: load x (exposed; TLP hides), P-trick pack, b128 writes
    {
      const int base = kc * 64 + sA_kg * 8;
      const int4 a0 = *(const int4*)&x[xrow + base];
      const int4 a1 = *(const int4*)&x[xrow + base + 4];
      const int c8v = (base + 8 < 512) ? x[xrow + base + 8] : 0;
      const u32 c0 = (u32)a0.x, c1 = (u32)a0.y, c2 = (u32)a0.z, c3 = (u32)a0.w;
      const u32 c4 = (u32)a1.x, c5 = (u32)a1.y, c6 = (u32)a1.z, c7 = (u32)a1.w;
      const u32 c8 = (u32)c8v;
      const u32 P0 = ((c0 << 8) | c1) | (((c1 << 8) | c2) << 16);
      const u32 P1 = ((c2 << 8) | c3) | (((c3 << 8) | c4) << 16);
      const u32 P2 = ((c4 << 8) | c5) | (((c5 << 8) | c6) << 16);
      const u32 P3 = ((c6 << 8) | c7) | (((c7 << 8) | c8) << 16);
      u16* arow = &As[(sA_sub * 8 + sA_qh * 4) * LSTRIDE + sA_kg * 8];
      #pragma unroll
      for (int qi = 0; qi < 4; ++qi) {
        const int sh = 8 - (sA_qh * 4 + qi);
        int4 d;
        d.x = (int)(((P0 >> sh) & 0x00FF00FFu) | 0x64006400u);
        d.y = (int)(((P1 >> sh) & 0x00FF00FFu) | 0x64006400u);
        d.z = (int)(((P2 >> sh) & 0x00FF00FFu) | 0x64006400u);
        d.w = (int)(((P3 >> sh) & 0x00FF00FFu) | 0x64006400u);
        *(int4*)(arow + qi * LSTRIDE) = d;   // rows 16B-aligned (144B pitch)
      }
    }

    // ---- stage B: 17 W loads (wave-uniform fast path for interior waves),
    // csum + cvt + pack, 4 b128 writes. All values transient in this phase.
    {
      const int cbase = kc * 64 + 16 * wave - 2 * y - 1;
      float fv[17];
      if (cbase >= 0 && cbase + 16 < 496) {   // wave-uniform branch
        const float* wp = &Wm[cbase * 64 + lane];
        #pragma unroll
        for (int j = 0; j < 17; ++j) fv[j] = wp[j * 64];
      } else {
        #pragma unroll
        for (int j = 0; j < 17; ++j) {
          const int c = cbase + j;
          fv[j] = (c >= 0 && c < 496) ? Wm[c * 64 + lane] : 0.0f;
        }
      }
      #pragma unroll
      for (int j = 1; j <= 16; ++j) csum_local += fv[j];  // pp=0: full W
      u32 hp[9];
      #pragma unroll
      for (int i = 0; i < 8; ++i) {
        u32 h0 = __builtin_bit_cast(unsigned short, (_Float16)fv[2 * i]);
        u32 h1 = __builtin_bit_cast(unsigned short, (_Float16)fv[2 * i + 1]);
        hp[i] = h0 | (h1 << 16);
      }
      hp[8] = (u32)__builtin_bit_cast(unsigned short, (_Float16)fv[16]);
      #pragma unroll
      for (int g = 0; g < 2; ++g) {
        const int mgrp = 2 * wave + g;
        int4 d1;                        // pp=1: even pairs, direct
        d1.x = (int)hp[4 * g + 0];
        d1.y = (int)hp[4 * g + 1];
        d1.z = (int)hp[4 * g + 2];
        d1.w = (int)hp[4 * g + 3];
        *(int4*)&Bs[(64 + lane) * LSTRIDE + mgrp * 8] = d1;
        int4 d0;                        // pp=0: odd pairs, alignbit extract
        d0.x = (int)((hp[4 * g + 0] >> 16) | (hp[4 * g + 1] << 16));
        d0.y = (int)((hp[4 * g + 1] >> 16) | (hp[4 * g + 2] << 16));
        d0.z = (int)((hp[4 * g + 2] >> 16) | (hp[4 * g + 3] << 16));
        d0.w = (int)((hp[4 * g + 3] >> 16) | (hp[4 * g + 4] << 16));
        *(int4*)&Bs[lane * LSTRIDE + mgrp * 8] = d0;
      }
    }
    __syncthreads();                   // tiles published

    // ---- compute: 2 k-steps of 32, aligned ds_read_b128 fragments
    #pragma unroll
    for (int ks = 0; ks < 2; ++ks) {
      const int koff = ks * 32 + quad * 8;
      half8 bf[4];
      #pragma unroll
      for (int nt = 0; nt < 4; ++nt)
        bf[nt] = *(const half8*)&Bs[(wn * 64 + nt * 16 + l16) * LSTRIDE + koff];
      #pragma unroll
      for (int mt = 0; mt < 4; ++mt) {
        half8 af =
            *(const half8*)&As[(wm * 64 + mt * 16 + l16) * LSTRIDE + koff];
        #pragma unroll
        for (int nt = 0; nt < 4; ++nt)
          acc[mt][nt] = __builtin_amdgcn_mfma_f32_16x16x32_f16(
              af, bf[nt], acc[mt][nt], 0, 0, 0);
      }
    }
  }

  // ---- csum reduction -> K1 * colsum(W)
  const float S = 2.0f / 255.0f;
  const float K1 = 1024.0f * S + 1.0f;
  part[t] = csum_local;
  __syncthreads();                     // also: all tile reads done, arena free
  if (t < 64)
    csumsh[t] = K1 * (part[t] + part[t + 64] + part[t + 128] + part[t + 192]);
  __syncthreads();

  float cs[4];
  #pragma unroll
  for (int nt = 0; nt < 4; ++nt) cs[nt] = csumsh[nt * 16 + l16];

  // ---- epilogue: two halves (8 subs each) staged in LDS (pitch 1040 f32),
  // then fully-coalesced stores: 64 lanes x 16B = 1KB contiguous per instr.
  float* ep = (float*)arena;           // 33280 B per half <= 36864
  #pragma unroll
  for (int h = 0; h < 2; ++h) {
    if (wm == h) {                     // waves wm==h own subs h*8..h*8+7
      #pragma unroll
      for (int mt = 0; mt < 4; ++mt)
        #pragma unroll
        for (int i = 0; i < 4; ++i) {
          const int mr = mt * 16 + quad * 4 + i;   // 0..63 local
          const int rowbase = (mr >> 3) * 1040 + wn * 512 + (mr & 7) * 64 + l16;
          #pragma unroll
          for (int nt = 0; nt < 4; ++nt)
            ep[rowbase + nt * 16] = __builtin_fmaf(S, acc[mt][nt][i], -cs[nt]);
        }
    }
    __syncthreads();
    const long outb =
        ((long)mtile * 16 + (long)h * 8) * 8192 + (long)y * 1024;
    #pragma unroll
    for (int k2 = 0; k2 < 8; ++k2) {
      const float4 v =
          *(const float4*)((const char*)ep + k2 * 4160 + wave * 1024 + lane * 16);
      *(float4*)&out[outb + (long)k2 * 8192 + wave * 256 + lane * 4] = v;
    }
    if (h == 0) __syncthreads();       // half-0 LDS reads done before re-stage
  }
}

extern "C" void kernel_launch(void* const* d_in, const int* in_sizes, int n_in,
                              void* d_out, int out_size, void* d_ws, size_t ws_size,
                              hipStream_t stream) {
  const int* x = (const int*)d_in[0];        // (256, 4096) byte values as int32
  const float* Wm = (const float*)d_in[1];   // (496, 64) fp32
  float* out = (float*)d_out;                // (256, 8, 128, 64) fp32
  byteformer_fused<<<dim3(128, 8), dim3(256), 0, stream>>>(x, Wm, out);
}